// Round 2
// baseline (474.274 us; speedup 1.0000x reference)
//
#include <hip/hip_runtime.h>

#define NB 16
#define NT 16384
#define ND 256
#define NS 4
#define SLICES 16
#define TPB 1024            // tokens per block (NT / SLICES)
#define CHUNK 32
#define NITER (TPB / CHUNK) // 32

typedef float          f32x4 __attribute__((ext_vector_type(4)));
typedef short          s16x8 __attribute__((ext_vector_type(8)));
typedef unsigned short u16x4 __attribute__((ext_vector_type(4)));

__device__ __forceinline__ unsigned short f2bf(float f) {
  unsigned int u = __float_as_uint(f);
  return (unsigned short)((u + 0x7FFFu + ((u >> 16) & 1u)) >> 16);
}

// One block = one (batch, slice of 1024 tokens), 1024 threads = 16 waves.
// Wave grid 4x4 over the 256x256 Gram (64x64 per wave -> 16 acc frags = 64 VGPR).
// Gvy folded into MFMA: per-wave one extra Y-column tile, B-fragment built in
// registers from a 2-bit packed speaker table. Partial Gram written with plain
// coalesced stores (no atomics); finalize reduces 16 slices and squares.
__global__ __launch_bounds__(1024) void fused_gram(
    const float* __restrict__ emb, const float* __restrict__ lab,
    float* __restrict__ P, float* __restrict__ PY, float* __restrict__ CntP)
{
  const int tid  = threadIdx.x;
  const int lane = tid & 63;
  const int w    = tid >> 6;           // wave 0..15
  const int b     = blockIdx.x >> 4;
  const int slice = blockIdx.x & 15;
  const int t0    = slice * TPB;

  __shared__ __align__(16) unsigned short rm[CHUNK * ND];    // 16 KB row-major bf16 chunk
  __shared__ __align__(16) unsigned short blkT[4 * ND * 8];  // 16 KB K-blocked [tg][d][8 tok]
  __shared__ unsigned int spk2[TPB / 16];                    // 256 B, 2-bit speaker ids
  __shared__ float cnt_l[NS];

  if (tid < TPB / 16) spk2[tid] = 0u;
  if (tid < NS) cnt_l[tid] = 0.0f;
  __syncthreads();

  // --- speaker decode: thread i owns token i (1024 threads = 1024 tokens) ---
  {
    f32x4 y = ((const f32x4*)(lab + ((size_t)b * NT + t0) * NS))[tid];
    int s = (int)(y.y + 2.0f * y.z + 3.0f * y.w + 0.5f);
    atomicOr(&spk2[tid >> 4], (unsigned)s << (2 * (tid & 15)));
    unsigned long long m0 = __ballot(s == 0);
    unsigned long long m1 = __ballot(s == 1);
    unsigned long long m2 = __ballot(s == 2);
    unsigned long long m3 = __ballot(s == 3);
    if (lane == 0) {
      atomicAdd(&cnt_l[0], (float)__popcll(m0));
      atomicAdd(&cnt_l[1], (float)__popcll(m1));
      atomicAdd(&cnt_l[2], (float)__popcll(m2));
      atomicAdd(&cnt_l[3], (float)__popcll(m3));
    }
  }

  const float* embB = emb + ((size_t)b * NT + t0) * ND;
  const int r = w >> 2, c = w & 3;     // wave tile: rows r*64, cols c*64

  f32x4 acc[4][4];
  f32x4 yacc = (f32x4){0.f, 0.f, 0.f, 0.f};
  #pragma unroll
  for (int i = 0; i < 4; ++i)
    #pragma unroll
    for (int j = 0; j < 4; ++j) acc[i][j] = (f32x4){0.f, 0.f, 0.f, 0.f};

  // prefetch chunk 0: wave w owns tokens 2w, 2w+1; lane holds dims 4l..4l+3
  f32x4 pf[2];
  #pragma unroll
  for (int j = 0; j < 2; ++j)
    pf[j] = *(const f32x4*)(embB + (size_t)(2 * w + j) * ND + 4 * lane);

  __syncthreads();   // spk2 / cnt_l ready

  const int quad = lane >> 4, m16 = lane & 15;

  for (int it = 0; it < NITER; ++it) {
    // ---- phase N: normalize 2 tokens/wave, write row-major bf16 to rm ----
    #pragma unroll
    for (int j = 0; j < 2; ++j) {
      f32x4 v = pf[j];
      float ss = v.x * v.x + v.y * v.y + v.z * v.z + v.w * v.w;
      #pragma unroll
      for (int off = 32; off; off >>= 1) ss += __shfl_xor(ss, off);
      float sc = 1.0f / fmaxf(sqrtf(ss), 1e-12f);
      u16x4 st;
      st.x = f2bf(v.x * sc); st.y = f2bf(v.y * sc);
      st.z = f2bf(v.z * sc); st.w = f2bf(v.w * sc);
      *(u16x4*)&rm[(2 * w + j) * ND + 4 * lane] = st;
    }
    // issue next chunk's global loads (in flight across T + M)
    if (it + 1 < NITER) {
      const float* p = embB + (size_t)((it + 1) * CHUNK + 2 * w) * ND + 4 * lane;
      #pragma unroll
      for (int j = 0; j < 2; ++j) pf[j] = *(const f32x4*)(p + j * ND);
    }
    __syncthreads();

    // ---- phase T: transpose to K-blocked layout. thread -> (tg, d) ----
    {
      int tg = tid >> 8, d = tid & 255;
      s16x8 v8;
      #pragma unroll
      for (int s8 = 0; s8 < 8; ++s8)
        v8[s8] = (short)rm[(tg * 8 + s8) * ND + d];
      *(s16x8*)&blkT[(tg * ND + d) * 8] = v8;   // 16B store, d-consecutive lanes
    }
    __syncthreads();

    // ---- phase M: one K=32 MFMA step over the chunk ----
    {
      const short* bp = (const short*)blkT;
      s16x8 afr[4];
      #pragma unroll
      for (int mi = 0; mi < 4; ++mi)
        afr[mi] = *(const s16x8*)(bp + ((quad * ND + (4 * r + mi) * 16 + m16) << 3));

      // Y column tile: B[k][n] = (spk[tok]==n), built from spk2 (broadcast read)
      {
        unsigned sw = spk2[it * 2 + (quad >> 1)];
        s16x8 y8;
        #pragma unroll
        for (int j = 0; j < 8; ++j) {
          int sp = (int)((sw >> (2 * ((quad & 1) * 8 + j))) & 3u);
          y8[j] = (sp == m16) ? (short)0x3F80 : (short)0;
        }
        yacc = __builtin_amdgcn_mfma_f32_16x16x32_bf16(afr[c], y8, yacc, 0, 0, 0);
      }

      #pragma unroll
      for (int nj = 0; nj < 4; ++nj) {
        s16x8 bfr = *(const s16x8*)(bp + ((quad * ND + (4 * c + nj) * 16 + m16) << 3));
        #pragma unroll
        for (int mi = 0; mi < 4; ++mi)
          acc[mi][nj] = __builtin_amdgcn_mfma_f32_16x16x32_bf16(afr[mi], bfr, acc[mi][nj], 0, 0, 0);
      }
    }
    // next N writes rm (T of this iter done at bar2); blkT rewritten only
    // after next bar1, by which time all waves finished this M.
  }

  // ---- epilogue: plain coalesced stores of the partial Gram ----
  {
    float* Pb = P + ((size_t)blockIdx.x << 16);
    #pragma unroll
    for (int mi = 0; mi < 4; ++mi)
      #pragma unroll
      for (int nj = 0; nj < 4; ++nj)
        #pragma unroll
        for (int rr = 0; rr < 4; ++rr) {
          int row = r * 64 + mi * 16 + quad * 4 + rr;  // C/D: row = quad*4+reg
          int col = c * 64 + nj * 16 + m16;            //      col = lane&15
          Pb[row * ND + col] = acc[mi][nj][rr];
        }
    float* PYb = PY + ((size_t)blockIdx.x << 12);
    #pragma unroll
    for (int rr = 0; rr < 4; ++rr)
      PYb[(w * 16 + quad * 4 + rr) * 16 + m16] = yacc[rr];
    if (tid < NS) CntP[blockIdx.x * NS + tid] = cnt_l[tid];
  }
}

// loss = sum_b [ sum(sum_s P)^2 - 2 sum(sum_s PY)^2 + sum(sum_s Cnt)^2 ] / (T*T*B)
__global__ __launch_bounds__(256) void finalize_kernel(
    const float* __restrict__ P, const float* __restrict__ PY,
    const float* __restrict__ CntP, float* __restrict__ out)
{
  const int b = blockIdx.x >> 4, seg = blockIdx.x & 15;
  const int tid = threadIdx.x;
  float local = 0.f;

  const float* Pb = P + ((size_t)b * 16) * 65536 + seg * 4096;
  #pragma unroll 4
  for (int k = 0; k < 16; ++k) {
    int e = tid + k * 256;
    float g = 0.f;
    #pragma unroll
    for (int s = 0; s < 16; ++s) g += Pb[(size_t)s * 65536 + e];
    local = fmaf(g, g, local);
  }
  if (seg == 0) {
    const float* Yb = PY + ((size_t)b * 16) * 4096;
    #pragma unroll 4
    for (int k = 0; k < 16; ++k) {
      int e = tid + k * 256;
      float g = 0.f;
      #pragma unroll
      for (int s = 0; s < 16; ++s) g += Yb[(size_t)s * 4096 + e];
      local = fmaf(-2.f * g, g, local);   // cols 4..15 are exactly 0
    }
    if (tid < NS) {
      float ct = 0.f;
      for (int s = 0; s < 16; ++s) ct += CntP[(b * 16 + s) * NS + tid];
      local = fmaf(ct, ct, local);
    }
  }
  #pragma unroll
  for (int off = 32; off; off >>= 1) local += __shfl_xor(local, off);
  __shared__ float wsum[4];
  if ((tid & 63) == 0) wsum[tid >> 6] = local;
  __syncthreads();
  if (tid == 0) {
    float s = wsum[0] + wsum[1] + wsum[2] + wsum[3];
    atomicAdd(out, s * (1.0f / 4294967296.0f));  // T*T*B = 2^32 exact
  }
}

extern "C" void kernel_launch(void* const* d_in, const int* in_sizes, int n_in,
                              void* d_out, int out_size, void* d_ws, size_t ws_size,
                              hipStream_t stream) {
  const float* emb = (const float*)d_in[0];  // [16,16384,256] fp32
  const float* lab = (const float*)d_in[1];  // [16,16384,4] fp32 one-hot
  float* out = (float*)d_out;

  float* P    = (float*)d_ws;                         // 256 * 65536 f32 = 64 MB
  float* PY   = P + (size_t)256 * 65536;              // 256 * 4096 f32 = 4 MB
  float* CntP = PY + (size_t)256 * 4096;              // 256 * 4 f32

  hipMemsetAsync(d_out, 0, sizeof(float), stream);

  fused_gram<<<dim3(NB * SLICES), dim3(1024), 0, stream>>>(emb, lab, P, PY, CntP);
  finalize_kernel<<<dim3(NB * SLICES), dim3(256), 0, stream>>>(P, PY, CntP, out);
}